// Round 5
// baseline (90.262 us; speedup 1.0000x reference)
//
#include <hip/hip_runtime.h>
#include <hip/hip_bf16.h>
#include <cstdint>

typedef __bf16 bf16x8 __attribute__((ext_vector_type(8)));
typedef float  f32x4  __attribute__((ext_vector_type(4)));

constexpr int RTOT  = 2304;          // 9 taps * 256 channels, r = k*256 + c
constexpr int RC    = 32;
constexpr int NSTEP = RTOT / RC;     // 72

#define WAITV4    asm volatile("s_waitcnt vmcnt(4)" ::: "memory")
#define WAITV0    asm volatile("s_waitcnt vmcnt(0)" ::: "memory")
#define WAITLGKM0 asm volatile("s_waitcnt lgkmcnt(0)" ::: "memory")
#define SCHEDB    __builtin_amdgcn_sched_barrier(0)

__device__ __forceinline__ float c2f(unsigned w, int hi) {
    union { unsigned u; float f; } v;
    v.u = hi ? (w & 0xffff0000u) : (w << 16);
    return v.f;
}

__device__ __forceinline__ float bf2f(unsigned short u) {
    union { unsigned int i; float f; } v; v.i = ((unsigned int)u) << 16; return v.f;
}

__device__ __forceinline__ void gload_lds16(const void* g, void* l) {
    __builtin_amdgcn_global_load_lds(
        (const __attribute__((address_space(1))) unsigned int*)g,
        (__attribute__((address_space(3))) unsigned int*)l, 16, 0, 0);
}

// ---- prep 1: x [4,256,64,64] f32 (NCHW) -> xh [4,64,64,256] bf16 (NHWC) ----
__global__ __launch_bounds__(256)
void nchw_to_nhwc_bf16(const float* __restrict__ x, __bf16* __restrict__ xh) {
    __shared__ unsigned short tile[256][70];
    const int tid = threadIdx.x;
    const int b = blockIdx.x >> 6;
    const int y = blockIdx.x & 63;
    const float* xp = x + (size_t)b * (256 * 4096) + y * 64;
    #pragma unroll 4
    for (int it = 0; it < 64; ++it) {
        const int ci = it * 4 + (tid >> 6);
        const int xi = tid & 63;
        __bf16 h = (__bf16)xp[(size_t)ci * 4096 + xi];
        tile[ci][xi] = *reinterpret_cast<unsigned short*>(&h);
    }
    __syncthreads();
    unsigned short* op = reinterpret_cast<unsigned short*>(xh) + ((size_t)b * 64 + y) * 64 * 256;
    #pragma unroll 4
    for (int it = 0; it < 64; ++it)
        op[(size_t)it * 256 + tid] = tile[tid][it];
}

// ---- prep 2: w [co][c][k] f32 -> wb [co][k*256+c] bf16 ----
__global__ __launch_bounds__(256)
void weight_prep(const float* __restrict__ w, __bf16* __restrict__ wb) {
    const int o = (blockIdx.x * 256 + threadIdx.x) * 4;
    const int co = o / 2304;
    const int rem = o - co * 2304;
    const int k = rem >> 8;
    const int c = rem & 255;
    union { ushort4 u; __bf16 h[4]; } pk;
    #pragma unroll
    for (int j = 0; j < 4; ++j)
        pk.h[j] = (__bf16)w[co * 2304 + (c + j) * 9 + k];
    *reinterpret_cast<ushort4*>(reinterpret_cast<unsigned short*>(wb) + o) = pk.u;
}

// ---- main: fused deformable implicit GEMM ----
// Block = 32 wo x 128 co (N-split halves), 256 threads / 4 waves; wave = 32(M) x 32(N).
// Grid = 1024 -> 4 blocks/CU (16 waves). Step t: tap k = t>>3, channels c0 = (t&7)*32.
// Pipeline per step: frag-reads(t) | B gload_lds(t+1) | MFMA(t) | combine A(t+1) |
//                    issue A(t+2) gathers | vmcnt(4) | barrier.
__global__ __launch_bounds__(256, 4)
void deform_gemm_nhwc(const float* __restrict__ off, const __bf16* __restrict__ xh,
                      const __bf16* __restrict__ wb, float* __restrict__ out) {
    __shared__ float4 s_w[32 * 9];
    __shared__ int4   s_a[32 * 9];
    __shared__ unsigned short sA[2][32 * 32];    // [p][r], XOR-swizzled 16B units
    __shared__ unsigned short sB[2][128 * 32];   // [co][r], XOR-swizzled 16B units

    const int tid  = threadIdx.x;
    const int lane = tid & 63;
    const int wv   = tid >> 6;
    const int fr   = lane & 15;
    const int fq   = lane >> 4;

    // XCD-chunked bijective swizzle (1024 % 8 == 0); co-half pairs stay adjacent -> same XCD
    const int bs  = ((blockIdx.x & 7) << 7) | (blockIdx.x >> 3);
    const int co0 = (bs & 1) << 7;
    const int wo0 = ((bs >> 1) & 1) << 5;
    const int ho  = (bs >> 2) & 63;
    const int b   = bs >> 8;

    for (int i = tid; i < 32 * 9; i += 256) {
        const int k = i >> 5, p = i & 31, wo = wo0 + p;
        const int kh = k / 3, kw = k - kh * 3;
        const float dy = off[(((b * 18) + 2 * k    ) * 64 + ho) * 64 + wo];
        const float dx = off[(((b * 18) + 2 * k + 1) * 64 + ho) * 64 + wo];
        const float sy = (float)(ho - 1 + kh) + dy;
        const float sx = (float)(wo - 1 + kw) + dx;
        const float y0f = floorf(sy), x0f = floorf(sx);
        const float fy = sy - y0f, fx = sx - x0f;
        const int y0 = (int)y0f, x0 = (int)x0f;
        const int y1 = y0 + 1, x1 = x0 + 1;
        const bool vy0 = (unsigned)y0 < 64u, vy1 = (unsigned)y1 < 64u;
        const bool vx0 = (unsigned)x0 < 64u, vx1 = (unsigned)x1 < 64u;
        const int y0c = min(max(y0, 0), 63), y1c = min(max(y1, 0), 63);
        const int x0c = min(max(x0, 0), 63), x1c = min(max(x1, 0), 63);
        float4 wt;
        wt.x = (1.f - fy) * (1.f - fx) * ((vy0 & vx0) ? 1.f : 0.f);
        wt.y = (1.f - fy) * fx         * ((vy0 & vx1) ? 1.f : 0.f);
        wt.z = fy * (1.f - fx)         * ((vy1 & vx0) ? 1.f : 0.f);
        wt.w = fy * fx                 * ((vy1 & vx1) ? 1.f : 0.f);
        s_w[i] = wt;
        s_a[i] = make_int4((y0c << 6) + x0c, (y0c << 6) + x1c,
                           (y1c << 6) + x0c, (y1c << 6) + x1c);
    }

    f32x4 acc[2][2];
    #pragma unroll
    for (int mf = 0; mf < 2; ++mf)
        #pragma unroll
        for (int nf = 0; nf < 2; ++nf)
            acc[mf][nf] = (f32x4){0.f, 0.f, 0.f, 0.f};

    const __bf16* xb = xh + ((size_t)b << 20);
    // Full-wave A-gen: each lane covers (position p, channel-quad cl) -> 4 channels.
    const int p  = tid >> 3;                 // 0..31
    const int cl = tid & 7;                  // c = c0 + cl*4
    const int aw_off = (p << 5) + ((((cl >> 1) ^ ((p >> 1) & 3)) << 3)) + ((cl & 1) << 2);
    const char* base_lane = (const char*)xb + (cl << 3);

    // B staging: 2 x 1KB gload_lds per wave (16 rows each)
    const __bf16* gpB[2];
    int bofs[2];
    #pragma unroll
    for (int q = 0; q < 2; ++q) {
        const int row = (wv << 5) + (q << 4) + (lane >> 2);
        const int u = (lane & 3) ^ ((row >> 1) & 3);
        gpB[q] = wb + (size_t)(co0 + row) * RTOT + (u << 3);
        bofs[q] = ((wv << 5) + (q << 4)) << 5;
    }

    __syncthreads();  // meta ready

    const char *aK0, *aK1, *aK2, *aK3;       // per-k corner base addresses (k-phase cached)
    float4 wt_k;
    uint2 ga0, ga1, ga2, ga3;

    {   // k = 0 meta into registers
        wt_k = s_w[p];
        const int4 sa = s_a[p];
        aK0 = base_lane + ((size_t)sa.x << 9);
        aK1 = base_lane + ((size_t)sa.y << 9);
        aK2 = base_lane + ((size_t)sa.z << 9);
        aK3 = base_lane + ((size_t)sa.w << 9);
    }

    // ---- prologue: B(0) + A(0) combine + issue A(1) ----
    {
        gload_lds16(gpB[0], &sB[0][bofs[0]]);
        gload_lds16(gpB[1], &sB[0][bofs[1]]);
        const uint2 g0 = *reinterpret_cast<const uint2*>(aK0);
        const uint2 g1 = *reinterpret_cast<const uint2*>(aK1);
        const uint2 g2 = *reinterpret_cast<const uint2*>(aK2);
        const uint2 g3 = *reinterpret_cast<const uint2*>(aK3);
        union { ushort4 u; __bf16 h[4]; } pk;
        pk.h[0] = (__bf16)(wt_k.x*c2f(g0.x,0)+wt_k.y*c2f(g1.x,0)+wt_k.z*c2f(g2.x,0)+wt_k.w*c2f(g3.x,0));
        pk.h[1] = (__bf16)(wt_k.x*c2f(g0.x,1)+wt_k.y*c2f(g1.x,1)+wt_k.z*c2f(g2.x,1)+wt_k.w*c2f(g3.x,1));
        pk.h[2] = (__bf16)(wt_k.x*c2f(g0.y,0)+wt_k.y*c2f(g1.y,0)+wt_k.z*c2f(g2.y,0)+wt_k.w*c2f(g3.y,0));
        pk.h[3] = (__bf16)(wt_k.x*c2f(g0.y,1)+wt_k.y*c2f(g1.y,1)+wt_k.z*c2f(g2.y,1)+wt_k.w*c2f(g3.y,1));
        *reinterpret_cast<ushort4*>(&sA[0][aw_off]) = pk.u;
        // issue A(1): same k, next 32-channel chunk (byte offset 64)
        ga0 = *reinterpret_cast<const uint2*>(aK0 + 64);
        ga1 = *reinterpret_cast<const uint2*>(aK1 + 64);
        ga2 = *reinterpret_cast<const uint2*>(aK2 + 64);
        ga3 = *reinterpret_cast<const uint2*>(aK3 + 64);
        SCHEDB;
        WAITV4;       // B(0) landed; A(1) x4 still in flight
        WAITLGKM0;
        __builtin_amdgcn_s_barrier();
        SCHEDB;
    }

    // ---- main loop: t = 0..70 computes step t, preps t+1, issues A(t+2) ----
    #pragma unroll 8
    for (int t = 0; t < NSTEP - 1; ++t) {
        const int cur = t & 1;
        const unsigned short* sAc = sA[cur];
        const unsigned short* sBc = sB[cur];
        unsigned short* sAn = const_cast<unsigned short*>(sA[cur ^ 1]);

        // 1) fragment reads
        bf16x8 af[2], bfr[2];
        #pragma unroll
        for (int mf = 0; mf < 2; ++mf) {
            const int row = mf * 16 + fr;
            af[mf] = *reinterpret_cast<const bf16x8*>(&sAc[(row << 5) + ((fq ^ ((row >> 1) & 3)) << 3)]);
        }
        #pragma unroll
        for (int nf = 0; nf < 2; ++nf) {
            const int row = (wv << 5) + nf * 16 + fr;
            bfr[nf] = *reinterpret_cast<const bf16x8*>(&sBc[(row << 5) + ((fq ^ ((row >> 1) & 3)) << 3)]);
        }

        // 2) B(t+1) gload_lds (oldest VMEM of this step)
        {
            const int r0n = (t + 1) << 5;
            gload_lds16(gpB[0] + r0n, &sB[cur ^ 1][bofs[0]]);
            gload_lds16(gpB[1] + r0n, &sB[cur ^ 1][bofs[1]]);
        }
        SCHEDB;

        // 3) MFMAs
        __builtin_amdgcn_s_setprio(1);
        acc[0][0] = __builtin_amdgcn_mfma_f32_16x16x32_bf16(af[0], bfr[0], acc[0][0], 0, 0, 0);
        acc[0][1] = __builtin_amdgcn_mfma_f32_16x16x32_bf16(af[0], bfr[1], acc[0][1], 0, 0, 0);
        acc[1][0] = __builtin_amdgcn_mfma_f32_16x16x32_bf16(af[1], bfr[0], acc[1][0], 0, 0, 0);
        acc[1][1] = __builtin_amdgcn_mfma_f32_16x16x32_bf16(af[1], bfr[1], acc[1][1], 0, 0, 0);
        __builtin_amdgcn_s_setprio(0);

        // 4) combine A(t+1) (auto counted-vmcnt on ga deps), write next buffer
        {
            union { ushort4 u; __bf16 h[4]; } pk;
            pk.h[0] = (__bf16)(wt_k.x*c2f(ga0.x,0)+wt_k.y*c2f(ga1.x,0)+wt_k.z*c2f(ga2.x,0)+wt_k.w*c2f(ga3.x,0));
            pk.h[1] = (__bf16)(wt_k.x*c2f(ga0.x,1)+wt_k.y*c2f(ga1.x,1)+wt_k.z*c2f(ga2.x,1)+wt_k.w*c2f(ga3.x,1));
            pk.h[2] = (__bf16)(wt_k.x*c2f(ga0.y,0)+wt_k.y*c2f(ga1.y,0)+wt_k.z*c2f(ga2.y,0)+wt_k.w*c2f(ga3.y,0));
            pk.h[3] = (__bf16)(wt_k.x*c2f(ga0.y,1)+wt_k.y*c2f(ga1.y,1)+wt_k.z*c2f(ga2.y,1)+wt_k.w*c2f(ga3.y,1));
            *reinterpret_cast<ushort4*>(&sAn[aw_off]) = pk.u;
        }
        SCHEDB;

        // 5) issue A(t+2); k-phase meta reload only when (t+2)%8 == 0 (static under unroll)
        if (t < NSTEP - 2) {
            const int t2 = t + 2;
            if ((t2 & 7) == 0) {
                const int k2 = t2 >> 3;
                wt_k = s_w[(k2 << 5) + p];
                const int4 sa = s_a[(k2 << 5) + p];
                aK0 = base_lane + ((size_t)sa.x << 9);
                aK1 = base_lane + ((size_t)sa.y << 9);
                aK2 = base_lane + ((size_t)sa.z << 9);
                aK3 = base_lane + ((size_t)sa.w << 9);
            }
            const int cb = (t2 & 7) << 6;   // byte offset within the k-phase
            ga0 = *reinterpret_cast<const uint2*>(aK0 + cb);
            ga1 = *reinterpret_cast<const uint2*>(aK1 + cb);
            ga2 = *reinterpret_cast<const uint2*>(aK2 + cb);
            ga3 = *reinterpret_cast<const uint2*>(aK3 + cb);
            SCHEDB;
            WAITV4;      // B(t+1) landed; A(t+2) x4 in flight across the barrier
        } else {
            SCHEDB;
            WAITV0;      // tail
        }
        WAITLGKM0;
        __builtin_amdgcn_s_barrier();
        SCHEDB;
    }

    // ---- final step t = 71 ----
    {
        const unsigned short* sAc = sA[(NSTEP - 1) & 1];
        const unsigned short* sBc = sB[(NSTEP - 1) & 1];
        bf16x8 af[2], bfr[2];
        #pragma unroll
        for (int mf = 0; mf < 2; ++mf) {
            const int row = mf * 16 + fr;
            af[mf] = *reinterpret_cast<const bf16x8*>(&sAc[(row << 5) + ((fq ^ ((row >> 1) & 3)) << 3)]);
        }
        #pragma unroll
        for (int nf = 0; nf < 2; ++nf) {
            const int row = (wv << 5) + nf * 16 + fr;
            bfr[nf] = *reinterpret_cast<const bf16x8*>(&sBc[(row << 5) + ((fq ^ ((row >> 1) & 3)) << 3)]);
        }
        acc[0][0] = __builtin_amdgcn_mfma_f32_16x16x32_bf16(af[0], bfr[0], acc[0][0], 0, 0, 0);
        acc[0][1] = __builtin_amdgcn_mfma_f32_16x16x32_bf16(af[0], bfr[1], acc[0][1], 0, 0, 0);
        acc[1][0] = __builtin_amdgcn_mfma_f32_16x16x32_bf16(af[1], bfr[0], acc[1][0], 0, 0, 0);
        acc[1][1] = __builtin_amdgcn_mfma_f32_16x16x32_bf16(af[1], bfr[1], acc[1][1], 0, 0, 0);
    }

    // ---- epilogue ----
    float* ob = out + (size_t)b * (256 * 4096) + (ho << 6) + wo0;
    #pragma unroll
    for (int nf = 0; nf < 2; ++nf) {
        const int n = co0 + (wv << 5) + nf * 16 + fr;
        #pragma unroll
        for (int mf = 0; mf < 2; ++mf) {
            const int m = mf * 16 + (fq << 2);
            *reinterpret_cast<f32x4*>(&ob[(size_t)n * 4096 + m]) = acc[mf][nf];
        }
    }
}

// ---- fallback (ws too small): convert-on-the-fly weights, NCHW gathers ----
__global__ __launch_bounds__(256, 2)
void deform_gemm_fb(const float* __restrict__ x, const float* __restrict__ off,
                    const float* __restrict__ wf, float* __restrict__ out) {
    __shared__ float4 s_w[32 * 9];
    __shared__ int4   s_a[32 * 9];
    __shared__ unsigned short sA[2][32 * 32];
    __shared__ unsigned short sB[2][256 * 32];

    const int tid  = threadIdx.x;
    const int lane = tid & 63;
    const int wv   = tid >> 6;
    const int fr   = lane & 15;
    const int fq   = lane >> 4;
    const int bs  = ((blockIdx.x & 7) << 6) | (blockIdx.x >> 3);
    const int b   = bs >> 7;
    const int ho  = (bs >> 1) & 63;
    const int wo0 = (bs & 1) << 5;

    for (int i = tid; i < 32 * 9; i += 256) {
        const int k = i >> 5, p = i & 31, wo = wo0 + p;
        const int kh = k / 3, kw = k - kh * 3;
        const float dy = off[(((b * 18) + 2 * k    ) * 64 + ho) * 64 + wo];
        const float dx = off[(((b * 18) + 2 * k + 1) * 64 + ho) * 64 + wo];
        const float sy = (float)(ho - 1 + kh) + dy;
        const float sx = (float)(wo - 1 + kw) + dx;
        const float y0f = floorf(sy), x0f = floorf(sx);
        const float fy = sy - y0f, fx = sx - x0f;
        const int y0 = (int)y0f, x0 = (int)x0f;
        const int y1 = y0 + 1, x1 = x0 + 1;
        const bool vy0 = (unsigned)y0 < 64u, vy1 = (unsigned)y1 < 64u;
        const bool vx0 = (unsigned)x0 < 64u, vx1 = (unsigned)x1 < 64u;
        const int y0c = min(max(y0, 0), 63), y1c = min(max(y1, 0), 63);
        const int x0c = min(max(x0, 0), 63), x1c = min(max(x1, 0), 63);
        float4 wt;
        wt.x = (1.f - fy) * (1.f - fx) * ((vy0 & vx0) ? 1.f : 0.f);
        wt.y = (1.f - fy) * fx         * ((vy0 & vx1) ? 1.f : 0.f);
        wt.z = fy * (1.f - fx)         * ((vy1 & vx0) ? 1.f : 0.f);
        wt.w = fy * fx                 * ((vy1 & vx1) ? 1.f : 0.f);
        s_w[i] = wt;
        s_a[i] = make_int4((y0c << 6) + x0c, (y0c << 6) + x1c,
                           (y1c << 6) + x0c, (y1c << 6) + x1c);
    }

    f32x4 acc[2][4];
    #pragma unroll
    for (int mf = 0; mf < 2; ++mf)
        #pragma unroll
        for (int nf = 0; nf < 4; ++nf)
            acc[mf][nf] = (f32x4){0.f, 0.f, 0.f, 0.f};

    const float* xb = x + (size_t)b * (256 * 4096);
    const int p  = tid & 31;
    const int rq = tid >> 5;
    const int aw_off = (p << 5) + ((((rq >> 1) ^ ((p >> 1) & 3)) << 3)) + ((rq & 1) << 2);

    int brow[4], bcol[4];
    #pragma unroll
    for (int q = 0; q < 4; ++q) {
        brow[q] = (wv << 6) + (q << 4) + (lane >> 2);
        bcol[q] = ((lane & 3) ^ ((brow[q] >> 1) & 3)) << 3;
    }
    const int bphys = (lane & 3) << 3;

    __syncthreads();

    for (int t = 0; t < NSTEP; ++t) {
        const int cur = t & 1;
        const int r0 = t * RC;
        union { ushort4 u; __bf16 h[4]; } pk;
        #pragma unroll
        for (int j = 0; j < 4; ++j) {
            const int r = r0 + rq * 4 + j;
            const int c = r / 9, k = r - c * 9;
            const float4 wt = s_w[(k << 5) + p];
            const int4 ad = s_a[(k << 5) + p];
            const float* xp = xb + (c << 12);
            pk.h[j] = (__bf16)(wt.x * xp[ad.x] + wt.y * xp[ad.y]
                             + wt.z * xp[ad.z] + wt.w * xp[ad.w]);
        }
        *reinterpret_cast<ushort4*>(&sA[cur][aw_off]) = pk.u;
        #pragma unroll
        for (int q = 0; q < 4; ++q) {
            const float4* s = reinterpret_cast<const float4*>(wf + (size_t)brow[q] * RTOT + r0 + bcol[q]);
            float4 f0 = s[0], f1 = s[1];
            union { uint4 u; __bf16 h[8]; } ub;
            ub.h[0]=(__bf16)f0.x; ub.h[1]=(__bf16)f0.y; ub.h[2]=(__bf16)f0.z; ub.h[3]=(__bf16)f0.w;
            ub.h[4]=(__bf16)f1.x; ub.h[5]=(__bf16)f1.y; ub.h[6]=(__bf16)f1.z; ub.h[7]=(__bf16)f1.w;
            *reinterpret_cast<uint4*>(&sB[cur][(brow[q] << 5) + bphys]) = ub.u;
        }
        __syncthreads();
        bf16x8 af[2], bfr[4];
        #pragma unroll
        for (int mf = 0; mf < 2; ++mf) {
            const int row = mf * 16 + fr;
            af[mf] = *reinterpret_cast<const bf16x8*>(&sA[cur][(row << 5) + ((fq ^ ((row >> 1) & 3)) << 3)]);
        }
        #pragma unroll
        for (int nf = 0; nf < 4; ++nf) {
            const int row = (wv << 6) + nf * 16 + fr;
            bfr[nf] = *reinterpret_cast<const bf16x8*>(&sB[cur][(row << 5) + ((fq ^ ((row >> 1) & 3)) << 3)]);
        }
        #pragma unroll
        for (int mf = 0; mf < 2; ++mf)
            #pragma unroll
            for (int nf = 0; nf < 4; ++nf)
                acc[mf][nf] = __builtin_amdgcn_mfma_f32_16x16x32_bf16(af[mf], bfr[nf], acc[mf][nf], 0, 0, 0);
        __syncthreads();
    }

    float* ob = out + (size_t)b * (256 * 4096) + (ho << 6) + wo0;
    #pragma unroll
    for (int nf = 0; nf < 4; ++nf) {
        const int n = (wv << 6) + nf * 16 + fr;
        #pragma unroll
        for (int mf = 0; mf < 2; ++mf) {
            const int m = mf * 16 + (fq << 2);
            *reinterpret_cast<f32x4*>(&ob[(size_t)n * 4096 + m]) = acc[mf][nf];
        }
    }
}

extern "C" void kernel_launch(void* const* d_in, const int* in_sizes, int n_in,
                              void* d_out, int out_size, void* d_ws, size_t ws_size,
                              hipStream_t stream) {
    const float* x   = (const float*)d_in[0];
    const float* off = (const float*)d_in[1];
    const float* w   = (const float*)d_in[2];
    float* out = (float*)d_out;

    const size_t xh_bytes = (size_t)4 * 64 * 64 * 256 * sizeof(__bf16);   // 8.4 MB
    const size_t wb_bytes = (size_t)256 * RTOT * sizeof(__bf16);          // 1.18 MB
    if (ws_size >= xh_bytes + wb_bytes) {
        __bf16* xh = (__bf16*)d_ws;
        __bf16* wb = (__bf16*)((char*)d_ws + xh_bytes);
        nchw_to_nhwc_bf16<<<dim3(256), dim3(256), 0, stream>>>(x, xh);
        weight_prep<<<dim3(576), dim3(256), 0, stream>>>(w, wb);
        deform_gemm_nhwc<<<dim3(1024), dim3(256), 0, stream>>>(off, xh, wb, out);
    } else {
        deform_gemm_fb<<<dim3(512), dim3(256), 0, stream>>>(x, off, w, out);
    }
}

// Round 6
// 75.889 us; speedup vs baseline: 1.1894x; 1.1894x over previous
//
#include <hip/hip_runtime.h>
#include <hip/hip_bf16.h>
#include <cstdint>

typedef __bf16 bf16x8 __attribute__((ext_vector_type(8)));
typedef float  f32x4  __attribute__((ext_vector_type(4)));

constexpr int RTOT  = 2304;          // 9 taps * 256 channels, r = k*256 + c
constexpr int RC    = 32;
constexpr int NSTEP = RTOT / RC;     // 72

#define WAITV4    asm volatile("s_waitcnt vmcnt(4)" ::: "memory")
#define WAITV0    asm volatile("s_waitcnt vmcnt(0)" ::: "memory")
#define WAITLGKM0 asm volatile("s_waitcnt lgkmcnt(0)" ::: "memory")
#define SCHEDB    __builtin_amdgcn_sched_barrier(0)

__device__ __forceinline__ float c2f(unsigned w, int hi) {
    union { unsigned u; float f; } v;
    v.u = hi ? (w & 0xffff0000u) : (w << 16);
    return v.f;
}

__device__ __forceinline__ void gload_lds16(const void* g, void* l) {
    __builtin_amdgcn_global_load_lds(
        (const __attribute__((address_space(1))) unsigned int*)g,
        (__attribute__((address_space(3))) unsigned int*)l, 16, 0, 0);
}

// ---- prep 1: x [4,256,64,64] f32 (NCHW) -> xh [4,64,64,256] bf16 (NHWC) ----
__global__ __launch_bounds__(256)
void nchw_to_nhwc_bf16(const float* __restrict__ x, __bf16* __restrict__ xh) {
    __shared__ unsigned short tile[256][70];
    const int tid = threadIdx.x;
    const int b = blockIdx.x >> 6;
    const int y = blockIdx.x & 63;
    const float* xp = x + (size_t)b * (256 * 4096) + y * 64;
    #pragma unroll 4
    for (int it = 0; it < 64; ++it) {
        const int ci = it * 4 + (tid >> 6);
        const int xi = tid & 63;
        __bf16 h = (__bf16)xp[(size_t)ci * 4096 + xi];
        tile[ci][xi] = *reinterpret_cast<unsigned short*>(&h);
    }
    __syncthreads();
    unsigned short* op = reinterpret_cast<unsigned short*>(xh) + ((size_t)b * 64 + y) * 64 * 256;
    #pragma unroll 4
    for (int it = 0; it < 64; ++it)
        op[(size_t)it * 256 + tid] = tile[tid][it];
}

// ---- prep 2: w [co][c][k] f32 -> wb [co][k*256+c] bf16 ----
__global__ __launch_bounds__(256)
void weight_prep(const float* __restrict__ w, __bf16* __restrict__ wb) {
    const int o = (blockIdx.x * 256 + threadIdx.x) * 4;
    const int co = o / 2304;
    const int rem = o - co * 2304;
    const int k = rem >> 8;
    const int c = rem & 255;
    union { ushort4 u; __bf16 h[4]; } pk;
    #pragma unroll
    for (int j = 0; j < 4; ++j)
        pk.h[j] = (__bf16)w[co * 2304 + (c + j) * 9 + k];
    *reinterpret_cast<ushort4*>(reinterpret_cast<unsigned short*>(wb) + o) = pk.u;
}

// ---- main: fused deformable implicit GEMM ----
// Block = 32 wo x 256 co, 512 threads / 8 waves (2M x 4N); wave slab = 16(M) x 64(N).
// Grid = 512 -> 2 blocks/CU = 16 waves/CU. Same traffic/work as the 4-wave version,
// double the TLP. Step t: tap k = t>>3, channels c0 = (t&7)*32.
// Pipeline: frag(t) | B gload_lds(t+1) | MFMA(t) | combine A(t+1) | issue A(t+2) |
//           vmcnt(4) | barrier.
__global__ __launch_bounds__(512, 4)
void deform_gemm_nhwc(const float* __restrict__ off, const __bf16* __restrict__ xh,
                      const __bf16* __restrict__ wb, float* __restrict__ out) {
    __shared__ float4 s_w[32 * 9];
    __shared__ int4   s_a[32 * 9];
    __shared__ unsigned short sA[2][32 * 32];    // [p][r], XOR-swizzled 16B units
    __shared__ unsigned short sB[2][256 * 32];   // [co][r], XOR-swizzled 16B units

    const int tid  = threadIdx.x;
    const int lane = tid & 63;
    const int wv   = tid >> 6;               // 0..7
    const int wm   = wv >> 2;                // M-half 0..1
    const int wn   = wv & 3;                 // N-quarter 0..3
    const int fr   = lane & 15;
    const int fq   = lane >> 4;

    const int bs  = ((blockIdx.x & 7) << 6) | (blockIdx.x >> 3);  // bijective XCD swizzle
    const int b   = bs >> 7;
    const int ho  = (bs >> 1) & 63;
    const int wo0 = (bs & 1) << 5;

    for (int i = tid; i < 32 * 9; i += 512) {
        const int k = i >> 5, p = i & 31, wo = wo0 + p;
        const int kh = k / 3, kw = k - kh * 3;
        const float dy = off[(((b * 18) + 2 * k    ) * 64 + ho) * 64 + wo];
        const float dx = off[(((b * 18) + 2 * k + 1) * 64 + ho) * 64 + wo];
        const float sy = (float)(ho - 1 + kh) + dy;
        const float sx = (float)(wo - 1 + kw) + dx;
        const float y0f = floorf(sy), x0f = floorf(sx);
        const float fy = sy - y0f, fx = sx - x0f;
        const int y0 = (int)y0f, x0 = (int)x0f;
        const int y1 = y0 + 1, x1 = x0 + 1;
        const bool vy0 = (unsigned)y0 < 64u, vy1 = (unsigned)y1 < 64u;
        const bool vx0 = (unsigned)x0 < 64u, vx1 = (unsigned)x1 < 64u;
        const int y0c = min(max(y0, 0), 63), y1c = min(max(y1, 0), 63);
        const int x0c = min(max(x0, 0), 63), x1c = min(max(x1, 0), 63);
        float4 wt;
        wt.x = (1.f - fy) * (1.f - fx) * ((vy0 & vx0) ? 1.f : 0.f);
        wt.y = (1.f - fy) * fx         * ((vy0 & vx1) ? 1.f : 0.f);
        wt.z = fy * (1.f - fx)         * ((vy1 & vx0) ? 1.f : 0.f);
        wt.w = fy * fx                 * ((vy1 & vx1) ? 1.f : 0.f);
        s_w[i] = wt;
        s_a[i] = make_int4((y0c << 6) + x0c, (y0c << 6) + x1c,
                           (y1c << 6) + x0c, (y1c << 6) + x1c);
    }

    f32x4 acc[4];
    #pragma unroll
    for (int nf = 0; nf < 4; ++nf)
        acc[nf] = (f32x4){0.f, 0.f, 0.f, 0.f};

    const __bf16* xb = xh + ((size_t)b << 20);
    // A-gen: 512 threads cover 32 positions x 16 channel-pairs (2 values/thread).
    const int p  = tid >> 4;                 // 0..31
    const int cl = tid & 15;                 // channel pair: c = c0 + cl*2
    // write: 2 values (4B) at row p, elems cl*2: unit u = cl>>2, word = cl&3
    const int aw_off = (p << 5) + ((((cl >> 2) ^ ((p >> 1) & 3)) << 3)) + ((cl & 3) << 1);
    const char* base_lane = (const char*)xb + (cl << 2);

    // B staging: wave wv stages rows [wv*32, wv*32+32) as 2 x 1KB gload_lds chunks
    const __bf16* gpB[2];
    int bofs[2];
    #pragma unroll
    for (int q = 0; q < 2; ++q) {
        const int row = (wv << 5) + (q << 4) + (lane >> 2);
        const int u = (lane & 3) ^ ((row >> 1) & 3);
        gpB[q] = wb + (size_t)row * RTOT + (u << 3);
        bofs[q] = ((wv << 5) + (q << 4)) << 5;
    }

    __syncthreads();  // meta ready

    const char *aK0, *aK1, *aK2, *aK3;       // per-tap corner base addresses
    float4 wt_k;
    unsigned ga0, ga1, ga2, ga3;

    {   // k = 0 meta into registers
        wt_k = s_w[p];
        const int4 sa = s_a[p];
        aK0 = base_lane + ((size_t)sa.x << 9);
        aK1 = base_lane + ((size_t)sa.y << 9);
        aK2 = base_lane + ((size_t)sa.z << 9);
        aK3 = base_lane + ((size_t)sa.w << 9);
    }

    // ---- prologue: B(0) + A(0) combine + issue A(1) ----
    {
        gload_lds16(gpB[0], &sB[0][bofs[0]]);
        gload_lds16(gpB[1], &sB[0][bofs[1]]);
        const unsigned g0 = *reinterpret_cast<const unsigned*>(aK0);
        const unsigned g1 = *reinterpret_cast<const unsigned*>(aK1);
        const unsigned g2 = *reinterpret_cast<const unsigned*>(aK2);
        const unsigned g3 = *reinterpret_cast<const unsigned*>(aK3);
        WAITV0;   // A(0) + B(0) landed
        union { unsigned u; __bf16 h[2]; } pk;
        pk.h[0] = (__bf16)(wt_k.x*c2f(g0,0)+wt_k.y*c2f(g1,0)+wt_k.z*c2f(g2,0)+wt_k.w*c2f(g3,0));
        pk.h[1] = (__bf16)(wt_k.x*c2f(g0,1)+wt_k.y*c2f(g1,1)+wt_k.z*c2f(g2,1)+wt_k.w*c2f(g3,1));
        *reinterpret_cast<unsigned*>(&sA[0][aw_off]) = pk.u;
        // issue A(1): same tap, next 32-channel chunk (byte offset 64)
        ga0 = *reinterpret_cast<const unsigned*>(aK0 + 64);
        ga1 = *reinterpret_cast<const unsigned*>(aK1 + 64);
        ga2 = *reinterpret_cast<const unsigned*>(aK2 + 64);
        ga3 = *reinterpret_cast<const unsigned*>(aK3 + 64);
        SCHEDB;
        WAITLGKM0;
        __builtin_amdgcn_s_barrier();
        SCHEDB;
    }

    // ---- main loop: t computes step t, preps t+1, issues A(t+2) ----
    #pragma unroll 8
    for (int t = 0; t < NSTEP - 1; ++t) {
        const int cur = t & 1;
        const unsigned short* sAc = sA[cur];
        const unsigned short* sBc = sB[cur];
        unsigned short* sAn = const_cast<unsigned short*>(sA[cur ^ 1]);

        // 1) fragment reads
        bf16x8 af, bfr[4];
        {
            const int arow = (wm << 4) + fr;
            af = *reinterpret_cast<const bf16x8*>(&sAc[(arow << 5) + ((fq ^ ((arow >> 1) & 3)) << 3)]);
        }
        #pragma unroll
        for (int nf = 0; nf < 4; ++nf) {
            const int row = (wn << 6) + nf * 16 + fr;
            bfr[nf] = *reinterpret_cast<const bf16x8*>(&sBc[(row << 5) + ((fq ^ ((row >> 1) & 3)) << 3)]);
        }

        // 2) B(t+1) gload_lds (oldest VMEM of this step)
        {
            const int r0n = (t + 1) << 5;
            gload_lds16(gpB[0] + r0n, &sB[cur ^ 1][bofs[0]]);
            gload_lds16(gpB[1] + r0n, &sB[cur ^ 1][bofs[1]]);
        }
        SCHEDB;

        // 3) MFMAs
        __builtin_amdgcn_s_setprio(1);
        acc[0] = __builtin_amdgcn_mfma_f32_16x16x32_bf16(af, bfr[0], acc[0], 0, 0, 0);
        acc[1] = __builtin_amdgcn_mfma_f32_16x16x32_bf16(af, bfr[1], acc[1], 0, 0, 0);
        acc[2] = __builtin_amdgcn_mfma_f32_16x16x32_bf16(af, bfr[2], acc[2], 0, 0, 0);
        acc[3] = __builtin_amdgcn_mfma_f32_16x16x32_bf16(af, bfr[3], acc[3], 0, 0, 0);
        __builtin_amdgcn_s_setprio(0);

        // 4) combine A(t+1) (compiler inserts counted vmcnt on ga deps), write next buffer
        {
            union { unsigned u; __bf16 h[2]; } pk;
            pk.h[0] = (__bf16)(wt_k.x*c2f(ga0,0)+wt_k.y*c2f(ga1,0)+wt_k.z*c2f(ga2,0)+wt_k.w*c2f(ga3,0));
            pk.h[1] = (__bf16)(wt_k.x*c2f(ga0,1)+wt_k.y*c2f(ga1,1)+wt_k.z*c2f(ga2,1)+wt_k.w*c2f(ga3,1));
            *reinterpret_cast<unsigned*>(&sAn[aw_off]) = pk.u;
        }
        SCHEDB;

        // 5) issue A(t+2); tap meta reload when (t+2)%8 == 0 (static under unroll 8)
        if (t < NSTEP - 2) {
            const int t2 = t + 2;
            if ((t2 & 7) == 0) {
                const int k2 = t2 >> 3;
                wt_k = s_w[(k2 << 5) + p];
                const int4 sa = s_a[(k2 << 5) + p];
                aK0 = base_lane + ((size_t)sa.x << 9);
                aK1 = base_lane + ((size_t)sa.y << 9);
                aK2 = base_lane + ((size_t)sa.z << 9);
                aK3 = base_lane + ((size_t)sa.w << 9);
            }
            const int cb = (t2 & 7) << 6;   // channel-chunk byte offset within the tap
            ga0 = *reinterpret_cast<const unsigned*>(aK0 + cb);
            ga1 = *reinterpret_cast<const unsigned*>(aK1 + cb);
            ga2 = *reinterpret_cast<const unsigned*>(aK2 + cb);
            ga3 = *reinterpret_cast<const unsigned*>(aK3 + cb);
            SCHEDB;
            WAITV4;      // B(t+1) landed; A(t+2) x4 in flight across the barrier
        } else {
            SCHEDB;
            WAITV0;      // tail
        }
        WAITLGKM0;
        __builtin_amdgcn_s_barrier();
        SCHEDB;
    }

    // ---- final step t = 71 ----
    {
        const unsigned short* sAc = sA[(NSTEP - 1) & 1];
        const unsigned short* sBc = sB[(NSTEP - 1) & 1];
        bf16x8 af, bfr[4];
        {
            const int arow = (wm << 4) + fr;
            af = *reinterpret_cast<const bf16x8*>(&sAc[(arow << 5) + ((fq ^ ((arow >> 1) & 3)) << 3)]);
        }
        #pragma unroll
        for (int nf = 0; nf < 4; ++nf) {
            const int row = (wn << 6) + nf * 16 + fr;
            bfr[nf] = *reinterpret_cast<const bf16x8*>(&sBc[(row << 5) + ((fq ^ ((row >> 1) & 3)) << 3)]);
        }
        acc[0] = __builtin_amdgcn_mfma_f32_16x16x32_bf16(af, bfr[0], acc[0], 0, 0, 0);
        acc[1] = __builtin_amdgcn_mfma_f32_16x16x32_bf16(af, bfr[1], acc[1], 0, 0, 0);
        acc[2] = __builtin_amdgcn_mfma_f32_16x16x32_bf16(af, bfr[2], acc[2], 0, 0, 0);
        acc[3] = __builtin_amdgcn_mfma_f32_16x16x32_bf16(af, bfr[3], acc[3], 0, 0, 0);
    }

    // ---- epilogue: D rows m = wm*16 + fq*4 + j, cols n = wn*64 + nf*16 + fr ----
    float* ob = out + (size_t)b * (256 * 4096) + (ho << 6) + wo0;
    #pragma unroll
    for (int nf = 0; nf < 4; ++nf) {
        const int n = (wn << 6) + nf * 16 + fr;
        const int m = (wm << 4) + (fq << 2);
        *reinterpret_cast<f32x4*>(&ob[(size_t)n * 4096 + m]) = acc[nf];
    }
}

// ---- fallback (ws too small): convert-on-the-fly weights, NCHW gathers ----
__global__ __launch_bounds__(256, 2)
void deform_gemm_fb(const float* __restrict__ x, const float* __restrict__ off,
                    const float* __restrict__ wf, float* __restrict__ out) {
    __shared__ float4 s_w[32 * 9];
    __shared__ int4   s_a[32 * 9];
    __shared__ unsigned short sA[2][32 * 32];
    __shared__ unsigned short sB[2][256 * 32];

    const int tid  = threadIdx.x;
    const int lane = tid & 63;
    const int wv   = tid >> 6;
    const int fr   = lane & 15;
    const int fq   = lane >> 4;
    const int bs  = ((blockIdx.x & 7) << 6) | (blockIdx.x >> 3);
    const int b   = bs >> 7;
    const int ho  = (bs >> 1) & 63;
    const int wo0 = (bs & 1) << 5;

    for (int i = tid; i < 32 * 9; i += 256) {
        const int k = i >> 5, p = i & 31, wo = wo0 + p;
        const int kh = k / 3, kw = k - kh * 3;
        const float dy = off[(((b * 18) + 2 * k    ) * 64 + ho) * 64 + wo];
        const float dx = off[(((b * 18) + 2 * k + 1) * 64 + ho) * 64 + wo];
        const float sy = (float)(ho - 1 + kh) + dy;
        const float sx = (float)(wo - 1 + kw) + dx;
        const float y0f = floorf(sy), x0f = floorf(sx);
        const float fy = sy - y0f, fx = sx - x0f;
        const int y0 = (int)y0f, x0 = (int)x0f;
        const int y1 = y0 + 1, x1 = x0 + 1;
        const bool vy0 = (unsigned)y0 < 64u, vy1 = (unsigned)y1 < 64u;
        const bool vx0 = (unsigned)x0 < 64u, vx1 = (unsigned)x1 < 64u;
        const int y0c = min(max(y0, 0), 63), y1c = min(max(y1, 0), 63);
        const int x0c = min(max(x0, 0), 63), x1c = min(max(x1, 0), 63);
        float4 wt;
        wt.x = (1.f - fy) * (1.f - fx) * ((vy0 & vx0) ? 1.f : 0.f);
        wt.y = (1.f - fy) * fx         * ((vy0 & vx1) ? 1.f : 0.f);
        wt.z = fy * (1.f - fx)         * ((vy1 & vx0) ? 1.f : 0.f);
        wt.w = fy * fx                 * ((vy1 & vx1) ? 1.f : 0.f);
        s_w[i] = wt;
        s_a[i] = make_int4((y0c << 6) + x0c, (y0c << 6) + x1c,
                           (y1c << 6) + x0c, (y1c << 6) + x1c);
    }

    f32x4 acc[2][4];
    #pragma unroll
    for (int mf = 0; mf < 2; ++mf)
        #pragma unroll
        for (int nf = 0; nf < 4; ++nf)
            acc[mf][nf] = (f32x4){0.f, 0.f, 0.f, 0.f};

    const float* xb = x + (size_t)b * (256 * 4096);
    const int p  = tid & 31;
    const int rq = tid >> 5;
    const int aw_off = (p << 5) + ((((rq >> 1) ^ ((p >> 1) & 3)) << 3)) + ((rq & 1) << 2);

    int brow[4], bcol[4];
    #pragma unroll
    for (int q = 0; q < 4; ++q) {
        brow[q] = (wv << 6) + (q << 4) + (lane >> 2);
        bcol[q] = ((lane & 3) ^ ((brow[q] >> 1) & 3)) << 3;
    }
    const int bphys = (lane & 3) << 3;

    __syncthreads();

    for (int t = 0; t < NSTEP; ++t) {
        const int cur = t & 1;
        const int r0 = t * RC;
        union { ushort4 u; __bf16 h[4]; } pk;
        #pragma unroll
        for (int j = 0; j < 4; ++j) {
            const int r = r0 + rq * 4 + j;
            const int c = r / 9, k = r - c * 9;
            const float4 wt = s_w[(k << 5) + p];
            const int4 ad = s_a[(k << 5) + p];
            const float* xp = xb + (c << 12);
            pk.h[j] = (__bf16)(wt.x * xp[ad.x] + wt.y * xp[ad.y]
                             + wt.z * xp[ad.z] + wt.w * xp[ad.w]);
        }
        *reinterpret_cast<ushort4*>(&sA[cur][aw_off]) = pk.u;
        #pragma unroll
        for (int q = 0; q < 4; ++q) {
            const float4* s = reinterpret_cast<const float4*>(wf + (size_t)brow[q] * RTOT + r0 + bcol[q]);
            float4 f0 = s[0], f1 = s[1];
            union { uint4 u; __bf16 h[8]; } ub;
            ub.h[0]=(__bf16)f0.x; ub.h[1]=(__bf16)f0.y; ub.h[2]=(__bf16)f0.z; ub.h[3]=(__bf16)f0.w;
            ub.h[4]=(__bf16)f1.x; ub.h[5]=(__bf16)f1.y; ub.h[6]=(__bf16)f1.z; ub.h[7]=(__bf16)f1.w;
            *reinterpret_cast<uint4*>(&sB[cur][(brow[q] << 5) + bphys]) = ub.u;
        }
        __syncthreads();
        bf16x8 af[2], bfr[4];
        #pragma unroll
        for (int mf = 0; mf < 2; ++mf) {
            const int row = mf * 16 + fr;
            af[mf] = *reinterpret_cast<const bf16x8*>(&sA[cur][(row << 5) + ((fq ^ ((row >> 1) & 3)) << 3)]);
        }
        #pragma unroll
        for (int nf = 0; nf < 4; ++nf) {
            const int row = (wv << 6) + nf * 16 + fr;
            bfr[nf] = *reinterpret_cast<const bf16x8*>(&sB[cur][(row << 5) + ((fq ^ ((row >> 1) & 3)) << 3)]);
        }
        #pragma unroll
        for (int mf = 0; mf < 2; ++mf)
            #pragma unroll
            for (int nf = 0; nf < 4; ++nf)
                acc[mf][nf] = __builtin_amdgcn_mfma_f32_16x16x32_bf16(af[mf], bfr[nf], acc[mf][nf], 0, 0, 0);
        __syncthreads();
    }

    float* ob = out + (size_t)b * (256 * 4096) + (ho << 6) + wo0;
    #pragma unroll
    for (int nf = 0; nf < 4; ++nf) {
        const int n = (wv << 6) + nf * 16 + fr;
        #pragma unroll
        for (int mf = 0; mf < 2; ++mf) {
            const int m = mf * 16 + (fq << 2);
            *reinterpret_cast<f32x4*>(&ob[(size_t)n * 4096 + m]) = acc[mf][nf];
        }
    }
}

extern "C" void kernel_launch(void* const* d_in, const int* in_sizes, int n_in,
                              void* d_out, int out_size, void* d_ws, size_t ws_size,
                              hipStream_t stream) {
    const float* x   = (const float*)d_in[0];
    const float* off = (const float*)d_in[1];
    const float* w   = (const float*)d_in[2];
    float* out = (float*)d_out;

    const size_t xh_bytes = (size_t)4 * 64 * 64 * 256 * sizeof(__bf16);   // 8.4 MB
    const size_t wb_bytes = (size_t)256 * RTOT * sizeof(__bf16);          // 1.18 MB
    if (ws_size >= xh_bytes + wb_bytes) {
        __bf16* xh = (__bf16*)d_ws;
        __bf16* wb = (__bf16*)((char*)d_ws + xh_bytes);
        nchw_to_nhwc_bf16<<<dim3(256), dim3(256), 0, stream>>>(x, xh);
        weight_prep<<<dim3(576), dim3(256), 0, stream>>>(w, wb);
        deform_gemm_nhwc<<<dim3(512), dim3(512), 0, stream>>>(off, xh, wb, out);
    } else {
        deform_gemm_fb<<<dim3(512), dim3(256), 0, stream>>>(x, off, w, out);
    }
}

// Round 7
// 64.096 us; speedup vs baseline: 1.4082x; 1.1840x over previous
//
#include <hip/hip_runtime.h>
#include <hip/hip_bf16.h>
#include <cstdint>

typedef __bf16 bf16x8 __attribute__((ext_vector_type(8)));
typedef float  f32x4  __attribute__((ext_vector_type(4)));
typedef unsigned short ushort8v __attribute__((ext_vector_type(8)));

constexpr int RTOT  = 2304;          // 9 taps * 256 channels, r = k*256 + c
constexpr int NSTEP = 72;            // RTOT / 32

#define WAITV5    asm volatile("s_waitcnt vmcnt(5)" ::: "memory")
#define WAITV1    asm volatile("s_waitcnt vmcnt(1)" ::: "memory")
#define WAITV0    asm volatile("s_waitcnt vmcnt(0)" ::: "memory")
#define WAITLGKM0 asm volatile("s_waitcnt lgkmcnt(0)" ::: "memory")
#define SCHEDB    __builtin_amdgcn_sched_barrier(0)

__device__ __forceinline__ float c2f(unsigned w, int hi) {
    union { unsigned u; float f; } v;
    v.u = hi ? (w & 0xffff0000u) : (w << 16);
    return v.f;
}

__device__ __forceinline__ void gload_lds16(const void* g, void* l) {
    __builtin_amdgcn_global_load_lds(
        (const __attribute__((address_space(1))) unsigned int*)g,
        (__attribute__((address_space(3))) unsigned int*)l, 16, 0, 0);
}

// ---- prep 1: x [4,256,64,64] f32 (NCHW) -> xh [4,64,64,256] bf16 (NHWC) ----
__global__ __launch_bounds__(256)
void nchw_to_nhwc_bf16(const float* __restrict__ x, __bf16* __restrict__ xh) {
    __shared__ unsigned short tile[256][70];
    const int tid = threadIdx.x;
    const int b = blockIdx.x >> 6;
    const int y = blockIdx.x & 63;
    const float* xp = x + (size_t)b * (256 * 4096) + y * 64;
    #pragma unroll 4
    for (int it = 0; it < 64; ++it) {
        const int ci = it * 4 + (tid >> 6);
        const int xi = tid & 63;
        __bf16 h = (__bf16)xp[(size_t)ci * 4096 + xi];
        tile[ci][xi] = *reinterpret_cast<unsigned short*>(&h);
    }
    __syncthreads();
    unsigned short* op = reinterpret_cast<unsigned short*>(xh) + ((size_t)b * 64 + y) * 64 * 256;
    #pragma unroll 4
    for (int it = 0; it < 64; ++it)
        op[(size_t)it * 256 + tid] = tile[tid][it];
}

// ---- prep 2: w [co][c][k] f32 -> wb [co][k*256+c] bf16 ----
__global__ __launch_bounds__(256)
void weight_prep(const float* __restrict__ w, __bf16* __restrict__ wb) {
    const int o = (blockIdx.x * 256 + threadIdx.x) * 4;
    const int co = o / 2304;
    const int rem = o - co * 2304;
    const int k = rem >> 8;
    const int c = rem & 255;
    union { ushort4 u; __bf16 h[4]; } pk;
    #pragma unroll
    for (int j = 0; j < 4; ++j)
        pk.h[j] = (__bf16)w[co * 2304 + (c + j) * 9 + k];
    *reinterpret_cast<ushort4*>(reinterpret_cast<unsigned short*>(wb) + o) = pk.u;
}

// ---- main: fused deformable implicit GEMM ----
// Block = 64 wo x 256 co (one full ho row), 1024 threads / 16 waves (4M x 4N).
// Grid = 256 -> 1 block/CU, 16 waves/CU. Step t: tap k = t>>3, channels (t&7)*32.
// Superstep = 4 steps (128 ch). A-gen: per superstep each thread gathers 4 corners
// x 8 ch (dwordx4) at phase 0, combines at phase 2, one ds_write_b128.
// B: 3-slot LDS ring, prefetch 2 steps ahead; wb padded so tail reads stay in-bounds.
// Static waits: ph0/ph1 vmcnt(5), ph2/ph3 vmcnt(1) -- never 0 in the loop.
__global__ __launch_bounds__(1024, 4)
void deform_gemm_nhwc(const float* __restrict__ off, const __bf16* __restrict__ xh,
                      const __bf16* __restrict__ wb, float* __restrict__ out) {
    __shared__ float4 s_w[64 * 9];
    __shared__ int4   s_a[64 * 9];
    __shared__ unsigned short sA[2][4 * 64 * 32];  // [buf][(sub*64+p)*32 + ch], swizzled
    __shared__ unsigned short sB[3][256 * 32];     // [slot][co*32 + ch], swizzled

    const int tid  = threadIdx.x;
    const int lane = tid & 63;
    const int wv   = tid >> 6;               // 0..15
    const int wm   = wv >> 2;                // M-quarter 0..3
    const int wn   = wv & 3;                 // N-quarter 0..3
    const int fr   = lane & 15;
    const int fq   = lane >> 4;

    const int bs = ((blockIdx.x & 7) << 5) | (blockIdx.x >> 3);  // bijective XCD swizzle
    const int b  = bs >> 6;
    const int ho = bs & 63;

    // ---- per-(k, p) bilinear metadata (64 positions x 9 taps) ----
    if (tid < 576) {
        const int i = tid;
        const int k = i >> 6, p = i & 63;
        const int kh = k / 3, kw = k - kh * 3;
        const float dy = off[(((b * 18) + 2 * k    ) * 64 + ho) * 64 + p];
        const float dx = off[(((b * 18) + 2 * k + 1) * 64 + ho) * 64 + p];
        const float sy = (float)(ho - 1 + kh) + dy;
        const float sx = (float)(p  - 1 + kw) + dx;
        const float y0f = floorf(sy), x0f = floorf(sx);
        const float fy = sy - y0f, fx = sx - x0f;
        const int y0 = (int)y0f, x0 = (int)x0f;
        const int y1 = y0 + 1, x1 = x0 + 1;
        const bool vy0 = (unsigned)y0 < 64u, vy1 = (unsigned)y1 < 64u;
        const bool vx0 = (unsigned)x0 < 64u, vx1 = (unsigned)x1 < 64u;
        const int y0c = min(max(y0, 0), 63), y1c = min(max(y1, 0), 63);
        const int x0c = min(max(x0, 0), 63), x1c = min(max(x1, 0), 63);
        float4 wt;
        wt.x = (1.f - fy) * (1.f - fx) * ((vy0 & vx0) ? 1.f : 0.f);
        wt.y = (1.f - fy) * fx         * ((vy0 & vx1) ? 1.f : 0.f);
        wt.z = fy * (1.f - fx)         * ((vy1 & vx0) ? 1.f : 0.f);
        wt.w = fy * fx                 * ((vy1 & vx1) ? 1.f : 0.f);
        s_w[i] = wt;
        s_a[i] = make_int4((y0c << 6) + x0c, (y0c << 6) + x1c,
                           (y1c << 6) + x0c, (y1c << 6) + x1c);
    }

    f32x4 acc[4];
    #pragma unroll
    for (int nf = 0; nf < 4; ++nf)
        acc[nf] = (f32x4){0.f, 0.f, 0.f, 0.f};

    const __bf16* xb = xh + ((size_t)b << 20);
    // A-gen: 1024 threads = 64 positions x 16 channel-octets (8 ch each / superstep)
    const int p   = tid >> 4;                // 0..63
    const int oct = tid & 15;                // c = oct*8 within the 128-ch superstep
    const int arow_w = ((oct >> 2) << 6) + p;            // sub*64 + p
    const int sw_w = ((arow_w >> 1) + (arow_w >> 6)) & 3;
    const int aw_off = (arow_w << 5) + ((((oct & 3) ^ sw_w)) << 3);
    const char* base_lane = (const char*)xb + (oct << 4);

    // B staging: wave wv stages rows [wv*16, wv*16+16) as one 1KB gload_lds per step
    const int brow = (wv << 4) + (lane >> 2);
    const int bu   = (lane & 3) ^ ((brow >> 1) & 3);
    const __bf16* gpB = wb + (size_t)brow * RTOT + (bu << 3);
    const int bofs = (wv << 4) << 5;

    __syncthreads();  // meta ready

    float4 wt_k;
    uint4 g0, g1, g2, g3;
    unsigned short* const sA0 = &sA[0][0];
    unsigned short* const sB0 = &sB[0][0];

    // ---- prologue: B(0), B(1); gather+combine superstep 0 into sA[0] ----
    {
        gload_lds16(gpB,      &sB[0][bofs]);
        gload_lds16(gpB + 32, &sB[1][bofs]);
        wt_k = s_w[p];                       // k = 0
        const int4 sa = s_a[p];
        g0 = *reinterpret_cast<const uint4*>(base_lane + ((size_t)sa.x << 9));
        g1 = *reinterpret_cast<const uint4*>(base_lane + ((size_t)sa.y << 9));
        g2 = *reinterpret_cast<const uint4*>(base_lane + ((size_t)sa.z << 9));
        g3 = *reinterpret_cast<const uint4*>(base_lane + ((size_t)sa.w << 9));
        const unsigned* w0 = reinterpret_cast<const unsigned*>(&g0);
        const unsigned* w1 = reinterpret_cast<const unsigned*>(&g1);
        const unsigned* w2 = reinterpret_cast<const unsigned*>(&g2);
        const unsigned* w3 = reinterpret_cast<const unsigned*>(&g3);
        union { ushort8v u; __bf16 h[8]; } pk;
        #pragma unroll
        for (int j = 0; j < 8; ++j)
            pk.h[j] = (__bf16)(wt_k.x * c2f(w0[j >> 1], j & 1) + wt_k.y * c2f(w1[j >> 1], j & 1)
                             + wt_k.z * c2f(w2[j >> 1], j & 1) + wt_k.w * c2f(w3[j >> 1], j & 1));
        *reinterpret_cast<ushort8v*>(&sA0[aw_off]) = pk.u;
        WAITV0;
        WAITLGKM0;
        __builtin_amdgcn_s_barrier();
        SCHEDB;
    }

    // ---- main loop: 72 steps, 4-phase supersteps, 3-slot B ring ----
    #pragma unroll 12
    for (int t = 0; t < NSTEP; ++t) {
        const int ph = t & 3;
        const int ss = t >> 2;
        const unsigned short* sAc = sA0 + ((ss & 1) << 13);
        const unsigned short* sBc = sB0 + (t % 3) * 8192;
        unsigned short* sBn = sB0 + ((t + 2) % 3) * 8192;

        // 1) fragment reads
        bf16x8 af, bfr[4];
        {
            const int ar = (ph << 6) + (wm << 4) + fr;
            const int s = ((ar >> 1) + (ar >> 6)) & 3;
            af = *reinterpret_cast<const bf16x8*>(&sAc[(ar << 5) + ((fq ^ s) << 3)]);
        }
        #pragma unroll
        for (int nf = 0; nf < 4; ++nf) {
            const int row = (wn << 6) + nf * 16 + fr;
            bfr[nf] = *reinterpret_cast<const bf16x8*>(&sBc[(row << 5) + ((fq ^ ((row >> 1) & 3)) << 3)]);
        }

        // 2) issue B(t+2) (wb is padded past RTOT so tail reads are in-bounds)
        gload_lds16(gpB + ((t + 2) << 5), &sBn[bofs]);

        // 3) phase 0: meta + gathers for superstep ss+1 (consumed at phase 2)
        if (ph == 0) {
            const int ssn = ss + 1;
            const int kk = (ssn < 18) ? (ssn >> 1) : 8;   // clamp keeps addrs valid
            wt_k = s_w[(kk << 6) + p];
            const int4 sa = s_a[(kk << 6) + p];
            const int cb = (ssn & 1) << 8;                // 0 or 128 ch * 2B
            g0 = *reinterpret_cast<const uint4*>(base_lane + ((size_t)sa.x << 9) + cb);
            g1 = *reinterpret_cast<const uint4*>(base_lane + ((size_t)sa.y << 9) + cb);
            g2 = *reinterpret_cast<const uint4*>(base_lane + ((size_t)sa.z << 9) + cb);
            g3 = *reinterpret_cast<const uint4*>(base_lane + ((size_t)sa.w << 9) + cb);
        }
        SCHEDB;

        // 4) MFMAs
        __builtin_amdgcn_s_setprio(1);
        acc[0] = __builtin_amdgcn_mfma_f32_16x16x32_bf16(af, bfr[0], acc[0], 0, 0, 0);
        acc[1] = __builtin_amdgcn_mfma_f32_16x16x32_bf16(af, bfr[1], acc[1], 0, 0, 0);
        acc[2] = __builtin_amdgcn_mfma_f32_16x16x32_bf16(af, bfr[2], acc[2], 0, 0, 0);
        acc[3] = __builtin_amdgcn_mfma_f32_16x16x32_bf16(af, bfr[3], acc[3], 0, 0, 0);
        __builtin_amdgcn_s_setprio(0);

        // 5) phase 2: combine superstep ss+1 (auto counted-vmcnt on g deps), write sA
        if (ph == 2) {
            unsigned short* sAw = sA0 + (((ss + 1) & 1) << 13);
            const unsigned* w0 = reinterpret_cast<const unsigned*>(&g0);
            const unsigned* w1 = reinterpret_cast<const unsigned*>(&g1);
            const unsigned* w2 = reinterpret_cast<const unsigned*>(&g2);
            const unsigned* w3 = reinterpret_cast<const unsigned*>(&g3);
            union { ushort8v u; __bf16 h[8]; } pk;
            #pragma unroll
            for (int j = 0; j < 8; ++j)
                pk.h[j] = (__bf16)(wt_k.x * c2f(w0[j >> 1], j & 1) + wt_k.y * c2f(w1[j >> 1], j & 1)
                                 + wt_k.z * c2f(w2[j >> 1], j & 1) + wt_k.w * c2f(w3[j >> 1], j & 1));
            *reinterpret_cast<ushort8v*>(&sAw[aw_off]) = pk.u;
        }
        SCHEDB;

        // 6) static pre-barrier waits (FIFO-derived; B(t+1) guaranteed landed)
        if (ph == 0 || ph == 1) { WAITV5; } else { WAITV1; }
        WAITLGKM0;
        __builtin_amdgcn_s_barrier();
        SCHEDB;
    }

    // ---- epilogue: rows m = wm*16 + fq*4 + j, cols n = wn*64 + nf*16 + fr ----
    float* ob = out + (size_t)b * (256 * 4096) + (ho << 6);
    #pragma unroll
    for (int nf = 0; nf < 4; ++nf) {
        const int n = (wn << 6) + nf * 16 + fr;
        const int m = (wm << 4) + (fq << 2);
        *reinterpret_cast<f32x4*>(&ob[(size_t)n * 4096 + m]) = acc[nf];
    }
}

// ---- fallback (ws too small): convert-on-the-fly weights, NCHW gathers ----
__global__ __launch_bounds__(256, 2)
void deform_gemm_fb(const float* __restrict__ x, const float* __restrict__ off,
                    const float* __restrict__ wf, float* __restrict__ out) {
    __shared__ float4 s_w[32 * 9];
    __shared__ int4   s_a[32 * 9];
    __shared__ unsigned short sA[2][32 * 32];
    __shared__ unsigned short sB[2][256 * 32];

    const int tid  = threadIdx.x;
    const int lane = tid & 63;
    const int wv   = tid >> 6;
    const int fr   = lane & 15;
    const int fq   = lane >> 4;
    const int bs  = ((blockIdx.x & 7) << 6) | (blockIdx.x >> 3);
    const int b   = bs >> 7;
    const int ho  = (bs >> 1) & 63;
    const int wo0 = (bs & 1) << 5;

    for (int i = tid; i < 32 * 9; i += 256) {
        const int k = i >> 5, p = i & 31, wo = wo0 + p;
        const int kh = k / 3, kw = k - kh * 3;
        const float dy = off[(((b * 18) + 2 * k    ) * 64 + ho) * 64 + wo];
        const float dx = off[(((b * 18) + 2 * k + 1) * 64 + ho) * 64 + wo];
        const float sy = (float)(ho - 1 + kh) + dy;
        const float sx = (float)(wo - 1 + kw) + dx;
        const float y0f = floorf(sy), x0f = floorf(sx);
        const float fy = sy - y0f, fx = sx - x0f;
        const int y0 = (int)y0f, x0 = (int)x0f;
        const int y1 = y0 + 1, x1 = x0 + 1;
        const bool vy0 = (unsigned)y0 < 64u, vy1 = (unsigned)y1 < 64u;
        const bool vx0 = (unsigned)x0 < 64u, vx1 = (unsigned)x1 < 64u;
        const int y0c = min(max(y0, 0), 63), y1c = min(max(y1, 0), 63);
        const int x0c = min(max(x0, 0), 63), x1c = min(max(x1, 0), 63);
        float4 wt;
        wt.x = (1.f - fy) * (1.f - fx) * ((vy0 & vx0) ? 1.f : 0.f);
        wt.y = (1.f - fy) * fx         * ((vy0 & vx1) ? 1.f : 0.f);
        wt.z = fy * (1.f - fx)         * ((vy1 & vx0) ? 1.f : 0.f);
        wt.w = fy * fx                 * ((vy1 & vx1) ? 1.f : 0.f);
        s_w[i] = wt;
        s_a[i] = make_int4((y0c << 6) + x0c, (y0c << 6) + x1c,
                           (y1c << 6) + x0c, (y1c << 6) + x1c);
    }

    f32x4 acc[2][4];
    #pragma unroll
    for (int mf = 0; mf < 2; ++mf)
        #pragma unroll
        for (int nf = 0; nf < 4; ++nf)
            acc[mf][nf] = (f32x4){0.f, 0.f, 0.f, 0.f};

    const float* xb = x + (size_t)b * (256 * 4096);
    const int p  = tid & 31;
    const int rq = tid >> 5;
    const int aw_off = (p << 5) + ((((rq >> 1) ^ ((p >> 1) & 3)) << 3)) + ((rq & 1) << 2);

    int brow[4], bcol[4];
    #pragma unroll
    for (int q = 0; q < 4; ++q) {
        brow[q] = (wv << 6) + (q << 4) + (lane >> 2);
        bcol[q] = ((lane & 3) ^ ((brow[q] >> 1) & 3)) << 3;
    }
    const int bphys = (lane & 3) << 3;

    __syncthreads();

    for (int t = 0; t < NSTEP; ++t) {
        const int cur = t & 1;
        const int r0 = t * 32;
        union { ushort4 u; __bf16 h[4]; } pk;
        #pragma unroll
        for (int j = 0; j < 4; ++j) {
            const int r = r0 + rq * 4 + j;
            const int c = r / 9, k = r - c * 9;
            const float4 wt = s_w[(k << 5) + p];
            const int4 ad = s_a[(k << 5) + p];
            const float* xp = xb + (c << 12);
            pk.h[j] = (__bf16)(wt.x * xp[ad.x] + wt.y * xp[ad.y]
                             + wt.z * xp[ad.z] + wt.w * xp[ad.w]);
        }
        *reinterpret_cast<ushort4*>(&sA[cur][aw_off]) = pk.u;
        #pragma unroll
        for (int q = 0; q < 4; ++q) {
            const float4* s = reinterpret_cast<const float4*>(wf + (size_t)brow[q] * RTOT + r0 + bcol[q]);
            float4 f0 = s[0], f1 = s[1];
            union { uint4 u; __bf16 h[8]; } ub;
            ub.h[0]=(__bf16)f0.x; ub.h[1]=(__bf16)f0.y; ub.h[2]=(__bf16)f0.z; ub.h[3]=(__bf16)f0.w;
            ub.h[4]=(__bf16)f1.x; ub.h[5]=(__bf16)f1.y; ub.h[6]=(__bf16)f1.z; ub.h[7]=(__bf16)f1.w;
            *reinterpret_cast<uint4*>(&sB[cur][(brow[q] << 5) + bphys]) = ub.u;
        }
        __syncthreads();
        bf16x8 af[2], bfr[4];
        #pragma unroll
        for (int mf = 0; mf < 2; ++mf) {
            const int row = mf * 16 + fr;
            af[mf] = *reinterpret_cast<const bf16x8*>(&sA[cur][(row << 5) + ((fq ^ ((row >> 1) & 3)) << 3)]);
        }
        #pragma unroll
        for (int nf = 0; nf < 4; ++nf) {
            const int row = (wv << 6) + nf * 16 + fr;
            bfr[nf] = *reinterpret_cast<const bf16x8*>(&sB[cur][(row << 5) + ((fq ^ ((row >> 1) & 3)) << 3)]);
        }
        #pragma unroll
        for (int mf = 0; mf < 2; ++mf)
            #pragma unroll
            for (int nf = 0; nf < 4; ++nf)
                acc[mf][nf] = __builtin_amdgcn_mfma_f32_16x16x32_bf16(af[mf], bfr[nf], acc[mf][nf], 0, 0, 0);
        __syncthreads();
    }

    float* ob = out + (size_t)b * (256 * 4096) + (ho << 6) + wo0;
    #pragma unroll
    for (int nf = 0; nf < 4; ++nf) {
        const int n = (wv << 6) + nf * 16 + fr;
        #pragma unroll
        for (int mf = 0; mf < 2; ++mf) {
            const int m = mf * 16 + (fq << 2);
            *reinterpret_cast<f32x4*>(&ob[(size_t)n * 4096 + m]) = acc[mf][nf];
        }
    }
}

extern "C" void kernel_launch(void* const* d_in, const int* in_sizes, int n_in,
                              void* d_out, int out_size, void* d_ws, size_t ws_size,
                              hipStream_t stream) {
    const float* x   = (const float*)d_in[0];
    const float* off = (const float*)d_in[1];
    const float* w   = (const float*)d_in[2];
    float* out = (float*)d_out;

    const size_t xh_bytes = (size_t)4 * 64 * 64 * 256 * sizeof(__bf16);   // 8.4 MB
    const size_t wb_bytes = (size_t)256 * RTOT * sizeof(__bf16);          // 1.18 MB
    const size_t pad_bytes = 4096;                                        // B tail over-read pad
    if (ws_size >= xh_bytes + wb_bytes + pad_bytes) {
        __bf16* xh = (__bf16*)d_ws;
        __bf16* wb = (__bf16*)((char*)d_ws + xh_bytes);
        nchw_to_nhwc_bf16<<<dim3(256), dim3(256), 0, stream>>>(x, xh);
        weight_prep<<<dim3(576), dim3(256), 0, stream>>>(w, wb);
        deform_gemm_nhwc<<<dim3(256), dim3(1024), 0, stream>>>(off, xh, wb, out);
    } else {
        deform_gemm_fb<<<dim3(512), dim3(256), 0, stream>>>(x, off, w, out);
    }
}

// Round 8
// 52.989 us; speedup vs baseline: 1.7034x; 1.2096x over previous
//
#include <hip/hip_runtime.h>
#include <hip/hip_bf16.h>
#include <cstdint>

typedef __bf16 bf16x8 __attribute__((ext_vector_type(8)));
typedef float  f32x4  __attribute__((ext_vector_type(4)));
typedef unsigned short ushort8v __attribute__((ext_vector_type(8)));

constexpr int RTOT  = 2304;          // 9 taps * 256 channels, r = k*256 + c
constexpr int NITER = 36;            // BK = 64 per iteration

#define WAITV4    asm volatile("s_waitcnt vmcnt(4)" ::: "memory")
#define WAITV0    asm volatile("s_waitcnt vmcnt(0)" ::: "memory")
#define WAITLGKM0 asm volatile("s_waitcnt lgkmcnt(0)" ::: "memory")
#define SCHEDB    __builtin_amdgcn_sched_barrier(0)

__device__ __forceinline__ float c2f(unsigned w, int hi) {
    union { unsigned u; float f; } v;
    v.u = hi ? (w & 0xffff0000u) : (w << 16);
    return v.f;
}

__device__ __forceinline__ void gload_lds16(const void* g, void* l) {
    __builtin_amdgcn_global_load_lds(
        (const __attribute__((address_space(1))) unsigned int*)g,
        (__attribute__((address_space(3))) unsigned int*)l, 16, 0, 0);
}

// ---- prep 1: x [4,256,64,64] f32 (NCHW) -> xh [4,64,64,256] bf16 (NHWC) ----
__global__ __launch_bounds__(256)
void nchw_to_nhwc_bf16(const float* __restrict__ x, __bf16* __restrict__ xh) {
    __shared__ unsigned short tile[256][70];
    const int tid = threadIdx.x;
    const int b = blockIdx.x >> 6;
    const int y = blockIdx.x & 63;
    const float* xp = x + (size_t)b * (256 * 4096) + y * 64;
    #pragma unroll 4
    for (int it = 0; it < 64; ++it) {
        const int ci = it * 4 + (tid >> 6);
        const int xi = tid & 63;
        __bf16 h = (__bf16)xp[(size_t)ci * 4096 + xi];
        tile[ci][xi] = *reinterpret_cast<unsigned short*>(&h);
    }
    __syncthreads();
    unsigned short* op = reinterpret_cast<unsigned short*>(xh) + ((size_t)b * 64 + y) * 64 * 256;
    #pragma unroll 4
    for (int it = 0; it < 64; ++it)
        op[(size_t)it * 256 + tid] = tile[tid][it];
}

// ---- prep 2: w [co][c][k] f32 -> wb [co][k*256+c] bf16 ----
__global__ __launch_bounds__(256)
void weight_prep(const float* __restrict__ w, __bf16* __restrict__ wb) {
    const int o = (blockIdx.x * 256 + threadIdx.x) * 4;
    const int co = o / 2304;
    const int rem = o - co * 2304;
    const int k = rem >> 8;
    const int c = rem & 255;
    union { ushort4 u; __bf16 h[4]; } pk;
    #pragma unroll
    for (int j = 0; j < 4; ++j)
        pk.h[j] = (__bf16)w[co * 2304 + (c + j) * 9 + k];
    *reinterpret_cast<ushort4*>(reinterpret_cast<unsigned short*>(wb) + o) = pk.u;
}

// ---- main: fused deformable implicit GEMM, BK=64 iterations ----
// Block = 64 wo x 256 co, 512 threads / 8 waves (2M x 4N); wave slab = 32(M) x 64(N).
// Grid = 256 -> 1 block/CU. Iter i covers r = i*64..i*64+63: tap k = i>>2,
// channel block c0 = (i&3)*64. Per iter: 12 ds_read_b128, 16 MFMA, 1 barrier.
// B: 3-slot 32KB ring staged 2 iters ahead (4 gload_lds/wave/iter).
// A: per thread 4 corner gathers (dwordx4, 8 ch) 1 iter ahead; combine at vmcnt(4);
//    one ds_write_b128 into the sA double buffer.
// LDS layout (A and B): row = 128B = 8 x 16B units, phys_unit = logical ^ (row&7).
__global__ __launch_bounds__(512, 1)
void deform_gemm_nhwc(const float* __restrict__ off, const __bf16* __restrict__ xh,
                      const __bf16* __restrict__ wb, float* __restrict__ out) {
    __shared__ float4 s_w[64 * 9];
    __shared__ int4   s_a[64 * 9];
    __shared__ unsigned short sA[2][64 * 64];    // [buf][p*64 + ch]
    __shared__ unsigned short sB[3][256 * 64];   // [slot][co*64 + ch]

    const int tid  = threadIdx.x;
    const int lane = tid & 63;
    const int wv   = tid >> 6;               // 0..7
    const int wm   = wv >> 2;                // M-half 0..1
    const int wn   = wv & 3;                 // N-quarter 0..3
    const int fr   = lane & 15;
    const int fq   = lane >> 4;

    const int bs = ((blockIdx.x & 7) << 5) | (blockIdx.x >> 3);  // bijective XCD swizzle
    const int b  = bs >> 6;
    const int ho = bs & 63;

    // ---- per-(k, p) bilinear metadata (9 taps x 64 positions) ----
    for (int i = tid; i < 576; i += 512) {
        const int k = i >> 6, p = i & 63;
        const int kh = k / 3, kw = k - kh * 3;
        const float dy = off[(((b * 18) + 2 * k    ) * 64 + ho) * 64 + p];
        const float dx = off[(((b * 18) + 2 * k + 1) * 64 + ho) * 64 + p];
        const float sy = (float)(ho - 1 + kh) + dy;
        const float sx = (float)(p  - 1 + kw) + dx;
        const float y0f = floorf(sy), x0f = floorf(sx);
        const float fy = sy - y0f, fx = sx - x0f;
        const int y0 = (int)y0f, x0 = (int)x0f;
        const int y1 = y0 + 1, x1 = x0 + 1;
        const bool vy0 = (unsigned)y0 < 64u, vy1 = (unsigned)y1 < 64u;
        const bool vx0 = (unsigned)x0 < 64u, vx1 = (unsigned)x1 < 64u;
        const int y0c = min(max(y0, 0), 63), y1c = min(max(y1, 0), 63);
        const int x0c = min(max(x0, 0), 63), x1c = min(max(x1, 0), 63);
        float4 wt;
        wt.x = (1.f - fy) * (1.f - fx) * ((vy0 & vx0) ? 1.f : 0.f);
        wt.y = (1.f - fy) * fx         * ((vy0 & vx1) ? 1.f : 0.f);
        wt.z = fy * (1.f - fx)         * ((vy1 & vx0) ? 1.f : 0.f);
        wt.w = fy * fx                 * ((vy1 & vx1) ? 1.f : 0.f);
        s_w[i] = wt;
        s_a[i] = make_int4((y0c << 6) + x0c, (y0c << 6) + x1c,
                           (y1c << 6) + x0c, (y1c << 6) + x1c);
    }

    f32x4 acc[2][4];
    #pragma unroll
    for (int mf = 0; mf < 2; ++mf)
        #pragma unroll
        for (int nf = 0; nf < 4; ++nf)
            acc[mf][nf] = (f32x4){0.f, 0.f, 0.f, 0.f};

    const __bf16* xb = xh + ((size_t)b << 20);
    // A-gen: 512 threads = 64 positions x 8 channel-octets (8 ch / thread / iter)
    const int p   = tid >> 3;                // 0..63
    const int oct = tid & 7;                 // c = oct*8 within the 64-ch iter block
    const int aw_off = (p << 6) + ((oct ^ (p & 7)) << 3);
    const char* base_lane = (const char*)xb + (oct << 4);

    // B staging: wave wv stages rows [wv*32, wv*32+32), 4 x 1KB gload_lds per iter
    const __bf16* gpB[4];
    int bofs[4];
    #pragma unroll
    for (int q = 0; q < 4; ++q) {
        const int row = (wv << 5) + (q << 3) + (lane >> 3);
        gpB[q] = wb + (size_t)row * RTOT + (((lane & 7) ^ (lane >> 3)) << 3);
        bofs[q] = ((wv << 5) + (q << 3)) << 6;
    }

    // fragment-read swizzled unit offsets (elems) for K32 halves s=0,1
    const int ua0 = ((0 * 4 + fq) ^ (fr & 7)) << 3;
    const int ua1 = ((1 * 4 + fq) ^ (fr & 7)) << 3;

    __syncthreads();  // meta ready

    float4 wt_k;
    uint4 ga0, ga1, ga2, ga3;
    const char *aK0, *aK1, *aK2, *aK3;

    {   // tap 0 meta
        wt_k = s_w[p];
        const int4 sa = s_a[p];
        aK0 = base_lane + ((size_t)sa.x << 9);
        aK1 = base_lane + ((size_t)sa.y << 9);
        aK2 = base_lane + ((size_t)sa.z << 9);
        aK3 = base_lane + ((size_t)sa.w << 9);
    }

    // ---- prologue: stage B(0),B(1); gather+combine A(0); issue A(1) ----
    {
        #pragma unroll
        for (int q = 0; q < 4; ++q) gload_lds16(gpB[q], &sB[0][bofs[q]]);
        #pragma unroll
        for (int q = 0; q < 4; ++q) gload_lds16(gpB[q] + 64, &sB[1][bofs[q]]);
        ga0 = *reinterpret_cast<const uint4*>(aK0);
        ga1 = *reinterpret_cast<const uint4*>(aK1);
        ga2 = *reinterpret_cast<const uint4*>(aK2);
        ga3 = *reinterpret_cast<const uint4*>(aK3);
        WAITV0;
        {
            const unsigned* w0 = reinterpret_cast<const unsigned*>(&ga0);
            const unsigned* w1 = reinterpret_cast<const unsigned*>(&ga1);
            const unsigned* w2 = reinterpret_cast<const unsigned*>(&ga2);
            const unsigned* w3 = reinterpret_cast<const unsigned*>(&ga3);
            union { ushort8v u; __bf16 h[8]; } pk;
            #pragma unroll
            for (int j = 0; j < 8; ++j)
                pk.h[j] = (__bf16)(wt_k.x * c2f(w0[j >> 1], j & 1) + wt_k.y * c2f(w1[j >> 1], j & 1)
                                 + wt_k.z * c2f(w2[j >> 1], j & 1) + wt_k.w * c2f(w3[j >> 1], j & 1));
            *reinterpret_cast<ushort8v*>(&sA[0][aw_off]) = pk.u;
        }
        // issue A(1): same tap, channel block 1 (byte offset 128)
        ga0 = *reinterpret_cast<const uint4*>(aK0 + 128);
        ga1 = *reinterpret_cast<const uint4*>(aK1 + 128);
        ga2 = *reinterpret_cast<const uint4*>(aK2 + 128);
        ga3 = *reinterpret_cast<const uint4*>(aK3 + 128);
        SCHEDB;
        WAITLGKM0;
        __builtin_amdgcn_s_barrier();
        SCHEDB;
    }

    // ---- main loop: 36 iterations of BK=64 ----
    #pragma unroll 4
    for (int i = 0; i < NITER; ++i) {
        const unsigned short* sAc = sA[i & 1];
        const unsigned short* sBc = sB[i % 3];
        unsigned short* sBn = const_cast<unsigned short*>(sB[(i + 2) % 3]);

        // 1) all 12 fragment reads (compiler schedules with counted lgkmcnt)
        bf16x8 a0[2], a1[2], b0[4], b1[4];
        #pragma unroll
        for (int mf = 0; mf < 2; ++mf) {
            const int ar = (wm << 5) + mf * 16 + fr;
            a0[mf] = *reinterpret_cast<const bf16x8*>(&sAc[(ar << 6) + ua0]);
            a1[mf] = *reinterpret_cast<const bf16x8*>(&sAc[(ar << 6) + ua1]);
        }
        #pragma unroll
        for (int nf = 0; nf < 4; ++nf) {
            const int br = (wn << 6) + nf * 16 + fr;
            b0[nf] = *reinterpret_cast<const bf16x8*>(&sBc[(br << 6) + ua0]);
            b1[nf] = *reinterpret_cast<const bf16x8*>(&sBc[(br << 6) + ua1]);
        }

        // 2) stage B(i+2) (oldest VMEM; wb padded so tail reads stay in-bounds)
        #pragma unroll
        for (int q = 0; q < 4; ++q)
            gload_lds16(gpB[q] + (size_t)(i + 2) * 64, &sBn[bofs[q]]);
        SCHEDB;

        // 3) MFMA K-half 0
        __builtin_amdgcn_s_setprio(1);
        #pragma unroll
        for (int mf = 0; mf < 2; ++mf)
            #pragma unroll
            for (int nf = 0; nf < 4; ++nf)
                acc[mf][nf] = __builtin_amdgcn_mfma_f32_16x16x32_bf16(a0[mf], b0[nf], acc[mf][nf], 0, 0, 0);
        __builtin_amdgcn_s_setprio(0);

        // 4) combine A(i+1): vmcnt(4) leaves B(i+2) in flight; write other sA buffer
        if (i < NITER - 1) {
            WAITV4;
            unsigned short* sAn = const_cast<unsigned short*>(sA[(i + 1) & 1]);
            const unsigned* w0 = reinterpret_cast<const unsigned*>(&ga0);
            const unsigned* w1 = reinterpret_cast<const unsigned*>(&ga1);
            const unsigned* w2 = reinterpret_cast<const unsigned*>(&ga2);
            const unsigned* w3 = reinterpret_cast<const unsigned*>(&ga3);
            union { ushort8v u; __bf16 h[8]; } pk;
            #pragma unroll
            for (int j = 0; j < 8; ++j)
                pk.h[j] = (__bf16)(wt_k.x * c2f(w0[j >> 1], j & 1) + wt_k.y * c2f(w1[j >> 1], j & 1)
                                 + wt_k.z * c2f(w2[j >> 1], j & 1) + wt_k.w * c2f(w3[j >> 1], j & 1));
            *reinterpret_cast<ushort8v*>(&sAn[aw_off]) = pk.u;
        }
        SCHEDB;

        // 5) issue A(i+2); tap meta reload when (i+2)%4 == 0 (static under unroll 4)
        if (i < NITER - 2) {
            const int ia = i + 2;
            if ((ia & 3) == 0) {
                const int kk = ia >> 2;
                wt_k = s_w[(kk << 6) + p];
                const int4 sa = s_a[(kk << 6) + p];
                aK0 = base_lane + ((size_t)sa.x << 9);
                aK1 = base_lane + ((size_t)sa.y << 9);
                aK2 = base_lane + ((size_t)sa.z << 9);
                aK3 = base_lane + ((size_t)sa.w << 9);
            }
            const int cb = (ia & 3) << 7;    // channel-block byte offset within the tap
            ga0 = *reinterpret_cast<const uint4*>(aK0 + cb);
            ga1 = *reinterpret_cast<const uint4*>(aK1 + cb);
            ga2 = *reinterpret_cast<const uint4*>(aK2 + cb);
            ga3 = *reinterpret_cast<const uint4*>(aK3 + cb);
        }
        SCHEDB;

        // 6) MFMA K-half 1
        __builtin_amdgcn_s_setprio(1);
        #pragma unroll
        for (int mf = 0; mf < 2; ++mf)
            #pragma unroll
            for (int nf = 0; nf < 4; ++nf)
                acc[mf][nf] = __builtin_amdgcn_mfma_f32_16x16x32_bf16(a1[mf], b1[nf], acc[mf][nf], 0, 0, 0);
        __builtin_amdgcn_s_setprio(0);

        // 7) ds ops visible, then barrier (B in flight stays in flight)
        WAITLGKM0;
        __builtin_amdgcn_s_barrier();
        SCHEDB;
    }

    // ---- epilogue: rows m = wm*32 + mf*16 + fq*4 + j, cols n = wn*64 + nf*16 + fr ----
    float* ob = out + (size_t)b * (256 * 4096) + (ho << 6);
    #pragma unroll
    for (int nf = 0; nf < 4; ++nf) {
        const int n = (wn << 6) + nf * 16 + fr;
        #pragma unroll
        for (int mf = 0; mf < 2; ++mf) {
            const int m = (wm << 5) + mf * 16 + (fq << 2);
            *reinterpret_cast<f32x4*>(&ob[(size_t)n * 4096 + m]) = acc[mf][nf];
        }
    }
}

// ---- fallback (ws too small): convert-on-the-fly weights, NCHW gathers ----
__global__ __launch_bounds__(256, 2)
void deform_gemm_fb(const float* __restrict__ x, const float* __restrict__ off,
                    const float* __restrict__ wf, float* __restrict__ out) {
    __shared__ float4 s_w[32 * 9];
    __shared__ int4   s_a[32 * 9];
    __shared__ unsigned short sA[2][32 * 32];
    __shared__ unsigned short sB[2][256 * 32];

    const int tid  = threadIdx.x;
    const int lane = tid & 63;
    const int wv   = tid >> 6;
    const int fr   = lane & 15;
    const int fq   = lane >> 4;
    const int bs  = ((blockIdx.x & 7) << 6) | (blockIdx.x >> 3);
    const int b   = bs >> 7;
    const int ho  = (bs >> 1) & 63;
    const int wo0 = (bs & 1) << 5;

    for (int i = tid; i < 32 * 9; i += 256) {
        const int k = i >> 5, p = i & 31, wo = wo0 + p;
        const int kh = k / 3, kw = k - kh * 3;
        const float dy = off[(((b * 18) + 2 * k    ) * 64 + ho) * 64 + wo];
        const float dx = off[(((b * 18) + 2 * k + 1) * 64 + ho) * 64 + wo];
        const float sy = (float)(ho - 1 + kh) + dy;
        const float sx = (float)(wo - 1 + kw) + dx;
        const float y0f = floorf(sy), x0f = floorf(sx);
        const float fy = sy - y0f, fx = sx - x0f;
        const int y0 = (int)y0f, x0 = (int)x0f;
        const int y1 = y0 + 1, x1 = x0 + 1;
        const bool vy0 = (unsigned)y0 < 64u, vy1 = (unsigned)y1 < 64u;
        const bool vx0 = (unsigned)x0 < 64u, vx1 = (unsigned)x1 < 64u;
        const int y0c = min(max(y0, 0), 63), y1c = min(max(y1, 0), 63);
        const int x0c = min(max(x0, 0), 63), x1c = min(max(x1, 0), 63);
        float4 wt;
        wt.x = (1.f - fy) * (1.f - fx) * ((vy0 & vx0) ? 1.f : 0.f);
        wt.y = (1.f - fy) * fx         * ((vy0 & vx1) ? 1.f : 0.f);
        wt.z = fy * (1.f - fx)         * ((vy1 & vx0) ? 1.f : 0.f);
        wt.w = fy * fx                 * ((vy1 & vx1) ? 1.f : 0.f);
        s_w[i] = wt;
        s_a[i] = make_int4((y0c << 6) + x0c, (y0c << 6) + x1c,
                           (y1c << 6) + x0c, (y1c << 6) + x1c);
    }

    f32x4 acc[2][4];
    #pragma unroll
    for (int mf = 0; mf < 2; ++mf)
        #pragma unroll
        for (int nf = 0; nf < 4; ++nf)
            acc[mf][nf] = (f32x4){0.f, 0.f, 0.f, 0.f};

    const float* xb = x + (size_t)b * (256 * 4096);
    const int p  = tid & 31;
    const int rq = tid >> 5;
    const int aw_off = (p << 5) + ((((rq >> 1) ^ ((p >> 1) & 3)) << 3)) + ((rq & 1) << 2);

    int brow[4], bcol[4];
    #pragma unroll
    for (int q = 0; q < 4; ++q) {
        brow[q] = (wv << 6) + (q << 4) + (lane >> 2);
        bcol[q] = ((lane & 3) ^ ((brow[q] >> 1) & 3)) << 3;
    }
    const int bphys = (lane & 3) << 3;

    __syncthreads();

    for (int t = 0; t < 72; ++t) {
        const int cur = t & 1;
        const int r0 = t * 32;
        union { ushort4 u; __bf16 h[4]; } pk;
        #pragma unroll
        for (int j = 0; j < 4; ++j) {
            const int r = r0 + rq * 4 + j;
            const int c = r / 9, k = r - c * 9;
            const float4 wt = s_w[(k << 5) + p];
            const int4 ad = s_a[(k << 5) + p];
            const float* xp = xb + (c << 12);
            pk.h[j] = (__bf16)(wt.x * xp[ad.x] + wt.y * xp[ad.y]
                             + wt.z * xp[ad.z] + wt.w * xp[ad.w]);
        }
        *reinterpret_cast<ushort4*>(&sA[cur][aw_off]) = pk.u;
        #pragma unroll
        for (int q = 0; q < 4; ++q) {
            const float4* s = reinterpret_cast<const float4*>(wf + (size_t)brow[q] * RTOT + r0 + bcol[q]);
            float4 f0 = s[0], f1 = s[1];
            union { uint4 u; __bf16 h[8]; } ub;
            ub.h[0]=(__bf16)f0.x; ub.h[1]=(__bf16)f0.y; ub.h[2]=(__bf16)f0.z; ub.h[3]=(__bf16)f0.w;
            ub.h[4]=(__bf16)f1.x; ub.h[5]=(__bf16)f1.y; ub.h[6]=(__bf16)f1.z; ub.h[7]=(__bf16)f1.w;
            *reinterpret_cast<uint4*>(&sB[cur][(brow[q] << 5) + bphys]) = ub.u;
        }
        __syncthreads();
        bf16x8 af[2], bfr[4];
        #pragma unroll
        for (int mf = 0; mf < 2; ++mf) {
            const int row = mf * 16 + fr;
            af[mf] = *reinterpret_cast<const bf16x8*>(&sA[cur][(row << 5) + ((fq ^ ((row >> 1) & 3)) << 3)]);
        }
        #pragma unroll
        for (int nf = 0; nf < 4; ++nf) {
            const int row = (wv << 6) + nf * 16 + fr;
            bfr[nf] = *reinterpret_cast<const bf16x8*>(&sB[cur][(row << 5) + ((fq ^ ((row >> 1) & 3)) << 3)]);
        }
        #pragma unroll
        for (int mf = 0; mf < 2; ++mf)
            #pragma unroll
            for (int nf = 0; nf < 4; ++nf)
                acc[mf][nf] = __builtin_amdgcn_mfma_f32_16x16x32_bf16(af[mf], bfr[nf], acc[mf][nf], 0, 0, 0);
        __syncthreads();
    }

    float* ob = out + (size_t)b * (256 * 4096) + (ho << 6) + wo0;
    #pragma unroll
    for (int nf = 0; nf < 4; ++nf) {
        const int n = (wv << 6) + nf * 16 + fr;
        #pragma unroll
        for (int mf = 0; mf < 2; ++mf) {
            const int m = mf * 16 + (fq << 2);
            *reinterpret_cast<f32x4*>(&ob[(size_t)n * 4096 + m]) = acc[mf][nf];
        }
    }
}

extern "C" void kernel_launch(void* const* d_in, const int* in_sizes, int n_in,
                              void* d_out, int out_size, void* d_ws, size_t ws_size,
                              hipStream_t stream) {
    const float* x   = (const float*)d_in[0];
    const float* off = (const float*)d_in[1];
    const float* w   = (const float*)d_in[2];
    float* out = (float*)d_out;

    const size_t xh_bytes = (size_t)4 * 64 * 64 * 256 * sizeof(__bf16);   // 8.4 MB
    const size_t wb_bytes = (size_t)256 * RTOT * sizeof(__bf16);          // 1.18 MB
    const size_t pad_bytes = 8192;                                        // B tail over-read pad
    if (ws_size >= xh_bytes + wb_bytes + pad_bytes) {
        __bf16* xh = (__bf16*)d_ws;
        __bf16* wb = (__bf16*)((char*)d_ws + xh_bytes);
        nchw_to_nhwc_bf16<<<dim3(256), dim3(256), 0, stream>>>(x, xh);
        weight_prep<<<dim3(576), dim3(256), 0, stream>>>(w, wb);
        deform_gemm_nhwc<<<dim3(256), dim3(512), 0, stream>>>(off, xh, wb, out);
    } else {
        deform_gemm_fb<<<dim3(512), dim3(256), 0, stream>>>(x, off, w, out);
    }
}